// Round 1
// baseline (196.976 us; speedup 1.0000x reference)
//
#include <hip/hip_runtime.h>

// ---------------------------------------------------------------------------
// Shapes (hardcoded from reference): B=4, N1=1024, N2=1024, D=256, H=4, Dh=64
// Decomposition:
//   u[b,i,4] = gelu(prev@W_pre+b_pre) @ W_fuse[0:6]
//   v[b,j,4] = gelu(curr@W_cur+b_cur) @ W_fuse[6:12] + b_fuse
//   c[b,i,j] = mask ? u_i + v_j : 0
//   d_j = (S_u + cnt*v_j)/(cnt+1);  e_j = f(masked-max u + v_j, anyUnmasked)
//   Gd_j[8] = gelu(d)@W_ffn[4:8] + gelu(e)@W_ffn[8:12] + b_ffn
//   fused_ij = gelu(c)@W_ffn[0:4] + Gd_j ; logits = gelu(fused)@W_fcc + b_fcc
//   softmax over i (masked), res = P @ prev (per-head 64 dims)
//   g_j = (T_j@W_ffn[0:4] + cnt*Gd_j)/(cnt+1), T_j = sum_mask gelu(c)
//   out = res + gelu(g)@W_fcg + b_fcg
// ---------------------------------------------------------------------------

__device__ __forceinline__ float gelu_f(float x){
    // 0.5*x*(1+tanh(0.79788456*(x+0.044715 x^3))) == x - x/(exp(2t)+1)
    float x3 = x*x*x;
    float t2 = 1.5957691216057308f * (x + 0.044715f*x3);
    float e  = __expf(t2);
    return x - __fdividef(x, e + 1.0f);
}

// ---- kernel 1: per-row u (prev side) and v (curr side), one wave per row ----
__global__ __launch_bounds__(256) void k_rows(
    const float* __restrict__ prev, const float* __restrict__ curr,
    const float* __restrict__ W_pre, const float* __restrict__ b_pre,
    const float* __restrict__ W_cur, const float* __restrict__ b_cur,
    const float* __restrict__ W_fuse, const float* __restrict__ b_fuse,
    float* __restrict__ u_ws, float* __restrict__ v_ws)
{
    int gid  = blockIdx.x * 256 + threadIdx.x;
    int wave = gid >> 6;
    int lane = threadIdx.x & 63;
    bool isPrev = wave < 4096;
    int row = isPrev ? wave : (wave - 4096);
    const float* xrow = (isPrev ? prev : curr) + (size_t)row * 256;
    const float* W  = isPrev ? W_pre : W_cur;
    const float* bv = isPrev ? b_pre : b_cur;

    float4 x4 = *reinterpret_cast<const float4*>(xrow + lane*4);
    const float* Wl = W + lane*24;               // rows 4*lane..4*lane+3, 6 wide
    float p[6];
    #pragma unroll
    for (int k=0;k<6;++k)
        p[k] = x4.x*Wl[k] + x4.y*Wl[6+k] + x4.z*Wl[12+k] + x4.w*Wl[18+k];
    #pragma unroll
    for (int off=32; off>=1; off>>=1){
        #pragma unroll
        for (int k=0;k<6;++k) p[k] += __shfl_xor(p[k], off, 64);
    }
    if (lane == 0){
        float g[6];
        #pragma unroll
        for(int k=0;k<6;++k) g[k] = gelu_f(p[k] + bv[k]);
        int rb = isPrev ? 0 : 6;
        float o[4];
        #pragma unroll
        for(int kk=0;kk<4;++kk){
            float a = isPrev ? 0.0f : b_fuse[kk];
            #pragma unroll
            for(int k=0;k<6;++k) a += g[k]*W_fuse[(rb+k)*4+kk];
            o[kk]=a;
        }
        float* dst = (isPrev ? u_ws : v_ws) + (size_t)row*4;
        *reinterpret_cast<float4*>(dst) = make_float4(o[0],o[1],o[2],o[3]);
    }
}

// ---- kernel 2: per-column reductions over edges + Gd precompute ----
// grid 256 blocks (b x 64 tiles of 16 cols); thread (jl = t&15, slice = t>>4)
__global__ __launch_bounds__(256) void k_cols(
    const int* __restrict__ edges,
    const float* __restrict__ u_ws, const float* __restrict__ v_ws,
    const float* __restrict__ W_ffn, const float* __restrict__ b_ffn,
    float* __restrict__ Gd_ws, float* __restrict__ cnt_ws)
{
    int b  = blockIdx.x >> 6;
    int j0 = (blockIdx.x & 63) * 16;
    int t  = threadIdx.x;
    int jl = t & 15, sl = t >> 4;
    const int*   eb = edges + (size_t)b*1024*1024;
    const float* ub = u_ws + (size_t)b*4096;

    int cnt = 0;
    float S0=0,S1=0,S2=0,S3=0;
    float M0=-3.4e38f,M1=-3.4e38f,M2=-3.4e38f,M3=-3.4e38f;
    int j = j0 + jl;
    for (int ii=0; ii<64; ++ii){
        int i = sl*64 + ii;
        int e = eb[(size_t)i*1024 + j];
        if (e){
            float4 u4 = *reinterpret_cast<const float4*>(ub + i*4);
            cnt++;
            S0+=u4.x; S1+=u4.y; S2+=u4.z; S3+=u4.w;
            M0=fmaxf(M0,u4.x); M1=fmaxf(M1,u4.y); M2=fmaxf(M2,u4.z); M3=fmaxf(M3,u4.w);
        }
    }
    __shared__ float rS[16][16][4], rM[16][16][4];
    __shared__ int   rC[16][16];
    rS[sl][jl][0]=S0; rS[sl][jl][1]=S1; rS[sl][jl][2]=S2; rS[sl][jl][3]=S3;
    rM[sl][jl][0]=M0; rM[sl][jl][1]=M1; rM[sl][jl][2]=M2; rM[sl][jl][3]=M3;
    rC[sl][jl]=cnt;
    __syncthreads();
    if (t < 16){
        int c=0; float Sa[4]={0,0,0,0};
        float Ma[4]={-3.4e38f,-3.4e38f,-3.4e38f,-3.4e38f};
        for(int s2=0;s2<16;++s2){
            c += rC[s2][t];
            #pragma unroll
            for(int k=0;k<4;++k){ Sa[k]+=rS[s2][t][k]; Ma[k]=fmaxf(Ma[k], rM[s2][t][k]); }
        }
        size_t cj = (size_t)b*1024 + j0 + t;
        float4 v4 = *reinterpret_cast<const float4*>(v_ws + cj*4);
        float vv[4]={v4.x,v4.y,v4.z,v4.w};
        float cf = (float)c, e1 = cf + 1.0f;
        float gd[4], ge[4];
        #pragma unroll
        for(int k=0;k<4;++k){
            float dk = (Sa[k] + cf*vv[k]) / e1;
            float ek;
            if (c == 0) ek = 0.0f;
            else { float m1 = Ma[k]+vv[k]; ek = (c < 1024) ? fmaxf(m1, 0.0f) : m1; }
            gd[k]=gelu_f(dk); ge[k]=gelu_f(ek);
        }
        #pragma unroll
        for(int kk=0;kk<8;++kk){
            float a = b_ffn[kk];
            #pragma unroll
            for(int k=0;k<4;++k)
                a += gd[k]*W_ffn[(4+k)*8+kk] + ge[k]*W_ffn[(8+k)*8+kk];
            Gd_ws[cj*8+kk]=a;
        }
        cnt_ws[cj]=cf;
    }
}

// ---- kernel 3: logits + online softmax + weighted prev + fused epilogue ----
// grid 512 blocks (b x 128 tiles of 8 cols), 256 threads.
// thread: jl = t&7 (column), h = (t>>3)&3 (head), dq = t>>5 (8-dim slice)
__global__ __launch_bounds__(256) void k_main(
    const float* __restrict__ prev, const int* __restrict__ edges,
    const float* __restrict__ u_ws, const float* __restrict__ v_ws,
    const float* __restrict__ Gd_ws, const float* __restrict__ cnt_ws,
    const float* __restrict__ W_ffn, const float* __restrict__ W_fcc,
    const float* __restrict__ b_fcc, const float* __restrict__ W_fcg,
    const float* __restrict__ b_fcg, float* __restrict__ out)
{
    int b  = blockIdx.x >> 7;
    int j0 = (blockIdx.x & 127) * 8;
    int t  = threadIdx.x;
    int jl = t & 7;
    int h  = (t >> 3) & 3;
    int dq = t >> 5;

    __shared__ float sLog[64][32];   // [i_local][jl*4+h], sentinel -1e30 unmasked
    __shared__ float sU[64][4];
    __shared__ float sV[8][4];
    __shared__ float sGd[8][8];
    __shared__ float sCnt[8];
    __shared__ float sT[32][8][4];
    __shared__ float sG[8][8];

    if (t < 32) (&sV[0][0])[t]  = v_ws[((size_t)b*1024 + j0)*4 + t];
    if (t < 64) (&sGd[0][0])[t] = Gd_ws[((size_t)b*1024 + j0)*8 + t];
    if (t < 8)  sCnt[t]         = cnt_ws[(size_t)b*1024 + j0 + t];

    // small weights in registers (broadcast global loads, cache-hot)
    float W4r[4][8], Wfc[8][4], bfc[4];
    #pragma unroll
    for(int k=0;k<4;++k)
        #pragma unroll
        for(int kk=0;kk<8;++kk) W4r[k][kk]=W_ffn[k*8+kk];
    #pragma unroll
    for(int kk=0;kk<8;++kk)
        #pragma unroll
        for(int hh=0;hh<4;++hh) Wfc[kk][hh]=W_fcc[kk*4+hh];
    #pragma unroll
    for(int hh=0;hh<4;++hh) bfc[hh]=b_fcc[hh];

    float m = -1e30f, s = 0.0f;
    float acc[8];
    #pragma unroll
    for(int d=0;d<8;++d) acc[d]=0.0f;
    float Tp[4] = {0,0,0,0};

    const int    qq    = jl*4 + h;
    const float* pbase = prev  + (size_t)b*1024*256 + h*64 + dq*8;
    const int*   ebase = edges + (size_t)b*1024*1024 + j0;

    for (int c16=0; c16<16; ++c16){
        int i0 = c16*64;
        __syncthreads();                                   // sLog/sU reuse
        (&sU[0][0])[t] = u_ws[((size_t)b*1024 + i0)*4 + t];
        __syncthreads();

        // ---- logit phase: 512 pairs, 2 per thread (same jl) ----
        #pragma unroll
        for (int r=0;r<2;++r){
            int il = (t >> 3) + 32*r;
            int eg = ebase[(size_t)(i0+il)*1024 + jl];
            float gc[4];
            #pragma unroll
            for(int k=0;k<4;++k){
                float cc = sU[il][k] + sV[jl][k];
                gc[k] = gelu_f(cc);
                Tp[k] += eg ? gc[k] : 0.0f;
            }
            float fu[8];
            #pragma unroll
            for(int kk=0;kk<8;++kk){
                float a = sGd[jl][kk];
                #pragma unroll
                for(int k=0;k<4;++k) a += gc[k]*W4r[k][kk];
                fu[kk] = gelu_f(a);
            }
            #pragma unroll
            for(int hh=0;hh<4;++hh){
                float a = bfc[hh];
                #pragma unroll
                for(int kk=0;kk<8;++kk) a += fu[kk]*Wfc[kk][hh];
                sLog[il][jl*4+hh] = eg ? a : -1e30f;
            }
        }
        __syncthreads();

        // ---- online softmax + accumulate ----
        float cm0=-1e30f,cm1=-1e30f,cm2=-1e30f,cm3=-1e30f;
        #pragma unroll 4
        for(int il=0; il<64; il+=4){
            cm0=fmaxf(cm0, sLog[il  ][qq]);
            cm1=fmaxf(cm1, sLog[il+1][qq]);
            cm2=fmaxf(cm2, sLog[il+2][qq]);
            cm3=fmaxf(cm3, sLog[il+3][qq]);
        }
        float cm = fmaxf(fmaxf(cm0,cm1), fmaxf(cm2,cm3));
        float mnew = fmaxf(m, cm);
        float sc = __expf(m - mnew);                       // m<=mnew always
        s *= sc;
        #pragma unroll
        for(int d=0;d<8;++d) acc[d]*=sc;
        m = mnew;

        const float* pc = pbase + (size_t)i0*256;
        #pragma unroll 4
        for(int il=0; il<64; ++il){
            float l = sLog[il][qq];
            float w = (l > -1e29f) ? __expf(l - m) : 0.0f;
            s += w;
            const float4* p4 = reinterpret_cast<const float4*>(pc + (size_t)il*256);
            float4 a0 = p4[0], a1 = p4[1];
            acc[0] += w*a0.x; acc[1] += w*a0.y; acc[2] += w*a0.z; acc[3] += w*a0.w;
            acc[4] += w*a1.x; acc[5] += w*a1.y; acc[6] += w*a1.z; acc[7] += w*a1.w;
        }
    }

    // ---- T reduction + g per column ----
    __syncthreads();
    {
        int sl2 = t >> 3;
        #pragma unroll
        for(int k=0;k<4;++k) sT[sl2][jl][k]=Tp[k];
    }
    __syncthreads();
    if (t < 8){
        float T0=0,T1=0,T2=0,T3=0;
        for(int s2=0;s2<32;++s2){
            T0+=sT[s2][t][0]; T1+=sT[s2][t][1]; T2+=sT[s2][t][2]; T3+=sT[s2][t][3];
        }
        float cf = sCnt[t], e1 = cf + 1.0f;
        float inv = __fdividef(1.0f, e1);
        #pragma unroll
        for(int kk=0;kk<8;++kk){
            float a = cf*sGd[t][kk]
                    + T0*W4r[0][kk]+T1*W4r[1][kk]+T2*W4r[2][kk]+T3*W4r[3][kk];
            sG[t][kk]=gelu_f(a*inv);
        }
    }
    __syncthreads();

    // ---- epilogue: normalize + gelu(g)@W_fcg + b_fcg ----
    float rs = (s > 0.0f) ? (1.0f/s) : 0.0f;   // s==0 <=> empty column -> res 0
    int col0 = h*64 + dq*8;
    float gg[8];
    #pragma unroll
    for(int kk=0;kk<8;++kk) gg[kk]=sG[jl][kk];
    float o[8];
    #pragma unroll
    for(int d=0;d<8;++d){
        float a = b_fcg[col0+d];
        #pragma unroll
        for(int kk=0;kk<8;++kk) a += gg[kk]*W_fcg[kk*256 + col0 + d];
        o[d] = acc[d]*rs + a;
    }
    float* ob = out + ((size_t)b*1024 + j0 + jl)*256 + col0;
    float4* o4 = reinterpret_cast<float4*>(ob);
    o4[0] = make_float4(o[0],o[1],o[2],o[3]);
    o4[1] = make_float4(o[4],o[5],o[6],o[7]);
}

extern "C" void kernel_launch(void* const* d_in, const int* in_sizes, int n_in,
                              void* d_out, int out_size, void* d_ws, size_t ws_size,
                              hipStream_t stream)
{
    const float* prev  = (const float*)d_in[0];
    const float* curr  = (const float*)d_in[1];
    const int*   edges = (const int*)  d_in[2];
    const float* W_pre = (const float*)d_in[3];
    const float* b_pre = (const float*)d_in[4];
    const float* W_cur = (const float*)d_in[5];
    const float* b_cur = (const float*)d_in[6];
    const float* W_fuse= (const float*)d_in[7];
    const float* b_fuse= (const float*)d_in[8];
    const float* W_ffn = (const float*)d_in[9];
    const float* b_ffn = (const float*)d_in[10];
    const float* W_fcc = (const float*)d_in[11];
    const float* b_fcc = (const float*)d_in[12];
    const float* W_fcg = (const float*)d_in[13];
    const float* b_fcg = (const float*)d_in[14];
    float* out = (float*)d_out;

    float* u_ws   = (float*)d_ws;          // 4*1024*4 = 16384 floats
    float* v_ws   = u_ws  + 16384;         // 16384
    float* Gd_ws  = v_ws  + 16384;         // 4*1024*8 = 32768
    float* cnt_ws = Gd_ws + 32768;         // 4096

    k_rows<<<dim3(2048), dim3(256), 0, stream>>>(prev, curr, W_pre, b_pre,
        W_cur, b_cur, W_fuse, b_fuse, u_ws, v_ws);
    k_cols<<<dim3(256), dim3(256), 0, stream>>>(edges, u_ws, v_ws,
        W_ffn, b_ffn, Gd_ws, cnt_ws);
    k_main<<<dim3(512), dim3(256), 0, stream>>>(prev, edges, u_ws, v_ws,
        Gd_ws, cnt_ws, W_ffn, W_fcc, b_fcc, W_fcg, b_fcg, out);
}

// Round 2
// 149.119 us; speedup vs baseline: 1.3209x; 1.3209x over previous
//
#include <hip/hip_runtime.h>

// ---------------------------------------------------------------------------
// Shapes (hardcoded from reference): B=4, N1=1024, N2=1024, D=256, H=4, Dh=64
// Decomposition:
//   u[b,i,4] = gelu(prev@W_pre+b_pre) @ W_fuse[0:6]
//   v[b,j,4] = gelu(curr@W_cur+b_cur) @ W_fuse[6:12] + b_fuse
//   c[b,i,j] = mask ? u_i + v_j : 0
//   d_j = (S_u + cnt*v_j)/(cnt+1);  e_j = f(masked-max u + v_j, anyUnmasked)
//   Gd_j[8] = gelu(d)@W_ffn[4:8] + gelu(e)@W_ffn[8:12] + b_ffn
//   fused_ij = gelu(c)@W_ffn[0:4] + Gd_j ; logits = gelu(fused)@W_fcc + b_fcc
//   softmax over i (masked), res = P @ prev (per-head 64 dims)
//   g_j = (T_j@W_ffn[0:4] + cnt*Gd_j)/(cnt+1), T_j = sum_mask gelu(c)
//   out = res + gelu(g)@W_fcg + b_fcg
// ---------------------------------------------------------------------------

__device__ __forceinline__ float gelu_f(float x){
    float x3 = x*x*x;
    float t2 = 1.5957691216057308f * (x + 0.044715f*x3);
    float e  = __expf(t2);
    return x - __fdividef(x, e + 1.0f);
}

// ---- kernel 1: per-row u (prev side) and v (curr side), one wave per row ----
__global__ __launch_bounds__(256) void k_rows(
    const float* __restrict__ prev, const float* __restrict__ curr,
    const float* __restrict__ W_pre, const float* __restrict__ b_pre,
    const float* __restrict__ W_cur, const float* __restrict__ b_cur,
    const float* __restrict__ W_fuse, const float* __restrict__ b_fuse,
    float* __restrict__ u_ws, float* __restrict__ v_ws)
{
    int gid  = blockIdx.x * 256 + threadIdx.x;
    int wave = gid >> 6;
    int lane = threadIdx.x & 63;
    bool isPrev = wave < 4096;
    int row = isPrev ? wave : (wave - 4096);
    const float* xrow = (isPrev ? prev : curr) + (size_t)row * 256;
    const float* W  = isPrev ? W_pre : W_cur;
    const float* bv = isPrev ? b_pre : b_cur;

    float4 x4 = *reinterpret_cast<const float4*>(xrow + lane*4);
    const float* Wl = W + lane*24;
    float p[6];
    #pragma unroll
    for (int k=0;k<6;++k)
        p[k] = x4.x*Wl[k] + x4.y*Wl[6+k] + x4.z*Wl[12+k] + x4.w*Wl[18+k];
    #pragma unroll
    for (int off=32; off>=1; off>>=1){
        #pragma unroll
        for (int k=0;k<6;++k) p[k] += __shfl_xor(p[k], off, 64);
    }
    if (lane == 0){
        float g[6];
        #pragma unroll
        for(int k=0;k<6;++k) g[k] = gelu_f(p[k] + bv[k]);
        int rb = isPrev ? 0 : 6;
        float o[4];
        #pragma unroll
        for(int kk=0;kk<4;++kk){
            float a = isPrev ? 0.0f : b_fuse[kk];
            #pragma unroll
            for(int k=0;k<6;++k) a += g[k]*W_fuse[(rb+k)*4+kk];
            o[kk]=a;
        }
        float* dst = (isPrev ? u_ws : v_ws) + (size_t)row*4;
        *reinterpret_cast<float4*>(dst) = make_float4(o[0],o[1],o[2],o[3]);
    }
}

// ---- kernel 2: per-column reductions over edges + Gd precompute ----
__global__ __launch_bounds__(256) void k_cols(
    const int* __restrict__ edges,
    const float* __restrict__ u_ws, const float* __restrict__ v_ws,
    const float* __restrict__ W_ffn, const float* __restrict__ b_ffn,
    float* __restrict__ Gd_ws, float* __restrict__ cnt_ws)
{
    int b  = blockIdx.x >> 6;
    int j0 = (blockIdx.x & 63) * 16;
    int t  = threadIdx.x;
    int jl = t & 15, sl = t >> 4;
    const int*   eb = edges + (size_t)b*1024*1024;
    const float* ub = u_ws + (size_t)b*4096;

    int cnt = 0;
    float S0=0,S1=0,S2=0,S3=0;
    float M0=-3.4e38f,M1=-3.4e38f,M2=-3.4e38f,M3=-3.4e38f;
    int j = j0 + jl;
    for (int ii=0; ii<64; ++ii){
        int i = sl*64 + ii;
        int e = eb[(size_t)i*1024 + j];
        if (e){
            float4 u4 = *reinterpret_cast<const float4*>(ub + i*4);
            cnt++;
            S0+=u4.x; S1+=u4.y; S2+=u4.z; S3+=u4.w;
            M0=fmaxf(M0,u4.x); M1=fmaxf(M1,u4.y); M2=fmaxf(M2,u4.z); M3=fmaxf(M3,u4.w);
        }
    }
    __shared__ float rS[16][16][4], rM[16][16][4];
    __shared__ int   rC[16][16];
    rS[sl][jl][0]=S0; rS[sl][jl][1]=S1; rS[sl][jl][2]=S2; rS[sl][jl][3]=S3;
    rM[sl][jl][0]=M0; rM[sl][jl][1]=M1; rM[sl][jl][2]=M2; rM[sl][jl][3]=M3;
    rC[sl][jl]=cnt;
    __syncthreads();
    if (t < 16){
        int c=0; float Sa[4]={0,0,0,0};
        float Ma[4]={-3.4e38f,-3.4e38f,-3.4e38f,-3.4e38f};
        for(int s2=0;s2<16;++s2){
            c += rC[s2][t];
            #pragma unroll
            for(int k=0;k<4;++k){ Sa[k]+=rS[s2][t][k]; Ma[k]=fmaxf(Ma[k], rM[s2][t][k]); }
        }
        size_t cj = (size_t)b*1024 + j0 + t;
        float4 v4 = *reinterpret_cast<const float4*>(v_ws + cj*4);
        float vv[4]={v4.x,v4.y,v4.z,v4.w};
        float cf = (float)c, e1 = cf + 1.0f;
        float gd[4], ge[4];
        #pragma unroll
        for(int k=0;k<4;++k){
            float dk = (Sa[k] + cf*vv[k]) / e1;
            float ek;
            if (c == 0) ek = 0.0f;
            else { float m1 = Ma[k]+vv[k]; ek = (c < 1024) ? fmaxf(m1, 0.0f) : m1; }
            gd[k]=gelu_f(dk); ge[k]=gelu_f(ek);
        }
        #pragma unroll
        for(int kk=0;kk<8;++kk){
            float a = b_ffn[kk];
            #pragma unroll
            for(int k=0;k<4;++k)
                a += gd[k]*W_ffn[(4+k)*8+kk] + ge[k]*W_ffn[(8+k)*8+kk];
            Gd_ws[cj*8+kk]=a;
        }
        cnt_ws[cj]=cf;
    }
}

// ---- kernel 3: logits + online softmax + weighted prev + fused epilogue ----
// Block = (b, 8 columns), 256 threads, grid 512.
// Logit-phase role:  (il_w = t>>3 in 0..31, jl_w = t&7)
// PV-phase role:     (dq = t&7, h = (t>>3)&3, ig = t>>5 in 0..7)
// Each PV thread accumulates ALL 8 columns for its (h, dq) over its i-slice;
// partial (s, acc) merged across ig at the end (identical m across ig).
__global__ __launch_bounds__(256) void k_main(
    const float* __restrict__ prev, const int* __restrict__ edges,
    const float* __restrict__ u_ws, const float* __restrict__ v_ws,
    const float* __restrict__ Gd_ws, const float* __restrict__ cnt_ws,
    const float* __restrict__ W_ffn, const float* __restrict__ W_fcc,
    const float* __restrict__ b_fcc, const float* __restrict__ W_fcg,
    const float* __restrict__ b_fcg, float* __restrict__ out)
{
    int b  = blockIdx.x >> 7;
    int j0 = (blockIdx.x & 127) * 8;
    int t  = threadIdx.x;
    int jl_w = t & 7;
    int il_w = t >> 3;
    int dq = t & 7;
    int h  = (t >> 3) & 3;
    int ig = t >> 5;

    __shared__ float sLog[64*34];    // [il][h*8+jl], row stride 34
    __shared__ float sU[64][4];
    __shared__ float sV[8][4];
    __shared__ float sGd[8][8];
    __shared__ float sCnt[8];
    __shared__ float sCMp[8][32];    // per-chunk max partials [qt][h*8+jl]
    __shared__ float sBig[9344];     // merge buffer (128*73) / sT(1024)+sG(64)

    if (t < 32) (&sV[0][0])[t]  = v_ws[((size_t)b*1024 + j0)*4 + t];
    if (t < 64) (&sGd[0][0])[t] = Gd_ws[((size_t)b*1024 + j0)*8 + t];
    if (t < 8)  sCnt[t]         = cnt_ws[(size_t)b*1024 + j0 + t];

    // small weights (uniform addresses -> scalar loads)
    float W4r[4][8], Wfc[8][4], bfc[4];
    #pragma unroll
    for(int k=0;k<4;++k)
        #pragma unroll
        for(int kk=0;kk<8;++kk) W4r[k][kk]=W_ffn[k*8+kk];
    #pragma unroll
    for(int kk=0;kk<8;++kk)
        #pragma unroll
        for(int hh=0;hh<4;++hh) Wfc[kk][hh]=W_fcc[kk*4+hh];
    #pragma unroll
    for(int hh=0;hh<4;++hh) bfc[hh]=b_fcc[hh];

    float m[8], s[8], acc[8][8];
    #pragma unroll
    for(int jl=0;jl<8;++jl){
        m[jl]=-1e30f; s[jl]=0.0f;
        #pragma unroll
        for(int d2=0;d2<8;++d2) acc[jl][d2]=0.0f;
    }
    float Tp[4] = {0,0,0,0};

    const int*   ebase  = edges + (size_t)b*1024*1024 + j0;
    const float* pbBase = prev  + (size_t)b*1024*256 + h*64 + dq*8;

    for (int c16=0; c16<16; ++c16){
        int i0 = c16*64;
        __syncthreads();                             // sLog/sU reuse
        (&sU[0][0])[t] = u_ws[((size_t)b*1024 + i0)*4 + t];
        __syncthreads();

        // ---- logit phase: 512 pairs, 2 per thread ----
        #pragma unroll
        for (int r=0;r<2;++r){
            int il = il_w + 32*r;
            int eg = ebase[(size_t)(i0+il)*1024 + jl_w];
            float gc[4];
            #pragma unroll
            for(int k=0;k<4;++k){
                float cc = sU[il][k] + sV[jl_w][k];
                gc[k] = gelu_f(cc);
                Tp[k] += eg ? gc[k] : 0.0f;
            }
            float fu[8];
            #pragma unroll
            for(int kk=0;kk<8;++kk){
                float a = sGd[jl_w][kk];
                #pragma unroll
                for(int k=0;k<4;++k) a += gc[k]*W4r[k][kk];
                fu[kk] = gelu_f(a);
            }
            #pragma unroll
            for(int hh=0;hh<4;++hh){
                float a = bfc[hh];
                #pragma unroll
                for(int kk=0;kk<8;++kk) a += fu[kk]*Wfc[kk][hh];
                sLog[il*34 + hh*8 + jl_w] = eg ? a : -1e30f;
            }
        }
        __syncthreads();

        // ---- chunk-max partials: each thread maxes 8 rows for one qq ----
        {
            int qq = t & 31, qt = t >> 5;
            float mm = sLog[(qt*8+0)*34 + qq];
            #pragma unroll
            for (int ii=1; ii<8; ++ii) mm = fmaxf(mm, sLog[(qt*8+ii)*34 + qq]);
            sCMp[qt][qq] = mm;
        }
        __syncthreads();

        // ---- rescale (m identical across ig: same sCMp sequence) ----
        #pragma unroll
        for (int jl=0;jl<8;++jl){
            int qq = h*8 + jl;
            float cm = sCMp[0][qq];
            #pragma unroll
            for (int k=1;k<8;++k) cm = fmaxf(cm, sCMp[k][qq]);
            float mo = m[jl];
            float mn = fmaxf(mo, cm);
            if (mn > mo){
                float sc = __expf(mo - mn);
                s[jl] *= sc;
                #pragma unroll
                for (int d2=0; d2<8; ++d2) acc[jl][d2] *= sc;
                m[jl] = mn;
            }
        }

        // ---- PV accumulate: this ig's 8 rows, all 8 columns ----
        {
            const float* pc  = pbBase + (size_t)(i0 + ig*8)*256;
            const float* lgb = sLog + (ig*8)*34 + h*8;
            #pragma unroll
            for (int ii=0; ii<8; ++ii){
                float4 a0 = *reinterpret_cast<const float4*>(pc + ii*256);
                float4 a1 = *reinterpret_cast<const float4*>(pc + ii*256 + 4);
                const float* lg = lgb + ii*34;
                float2 w01 = *reinterpret_cast<const float2*>(lg);
                float2 w23 = *reinterpret_cast<const float2*>(lg+2);
                float2 w45 = *reinterpret_cast<const float2*>(lg+4);
                float2 w67 = *reinterpret_cast<const float2*>(lg+6);
                float l[8] = {w01.x,w01.y,w23.x,w23.y,w45.x,w45.y,w67.x,w67.y};
                #pragma unroll
                for (int jl=0;jl<8;++jl){
                    float w = (l[jl] > -1e29f) ? __expf(l[jl]-m[jl]) : 0.0f;
                    s[jl] += w;
                    acc[jl][0]+=w*a0.x; acc[jl][1]+=w*a0.y;
                    acc[jl][2]+=w*a0.z; acc[jl][3]+=w*a0.w;
                    acc[jl][4]+=w*a1.x; acc[jl][5]+=w*a1.y;
                    acc[jl][6]+=w*a1.z; acc[jl][7]+=w*a1.w;
                }
            }
        }
    }

    // ---- merge partial (s, acc) across ig (m identical -> plain sums) ----
    {
        int role = t & 31;
        #pragma unroll
        for (int stride=4; stride>=1; stride>>=1){
            __syncthreads();
            if (ig >= stride && ig < 2*stride){
                float* dst = sBig + (size_t)((ig-stride)*32 + role)*73;
                #pragma unroll
                for (int jl=0;jl<8;++jl) dst[jl] = s[jl];
                #pragma unroll
                for (int jl=0;jl<8;++jl)
                    #pragma unroll
                    for (int d2=0;d2<8;++d2) dst[8+jl*8+d2] = acc[jl][d2];
            }
            __syncthreads();
            if (ig < stride){
                const float* src = sBig + (size_t)(ig*32 + role)*73;
                #pragma unroll
                for (int jl=0;jl<8;++jl) s[jl] += src[jl];
                #pragma unroll
                for (int jl=0;jl<8;++jl)
                    #pragma unroll
                    for (int d2=0;d2<8;++d2) acc[jl][d2] += src[8+jl*8+d2];
            }
        }
    }

    // ---- T reduction + g per column (sBig reused as sT[32][8][4] + sG) ----
    __syncthreads();
    #pragma unroll
    for(int k=0;k<4;++k) sBig[((il_w*8 + jl_w)*4) + k] = Tp[k];
    __syncthreads();
    float* sG = sBig + 1024;   // [8][8]
    if (t < 8){
        float T0=0,T1=0,T2=0,T3=0;
        for(int s2=0;s2<32;++s2){
            const float* p = sBig + (s2*8 + t)*4;
            T0+=p[0]; T1+=p[1]; T2+=p[2]; T3+=p[3];
        }
        float cf = sCnt[t];
        float inv = __fdividef(1.0f, cf + 1.0f);
        #pragma unroll
        for(int kk=0;kk<8;++kk){
            float a = cf*sGd[t][kk]
                    + T0*W4r[0][kk]+T1*W4r[1][kk]+T2*W4r[2][kk]+T3*W4r[3][kk];
            sG[t*8+kk]=gelu_f(a*inv);
        }
    }
    __syncthreads();

    // ---- epilogue: ig==0 threads hold merged state for (h, dq) ----
    if (t < 32){
        int col0 = h*64 + dq*8;
        #pragma unroll
        for (int jl=0;jl<8;++jl){
            float rs = (s[jl] > 0.0f) ? (1.0f/s[jl]) : 0.0f;
            float gg[8];
            #pragma unroll
            for(int kk=0;kk<8;++kk) gg[kk]=sG[jl*8+kk];
            float o[8];
            #pragma unroll
            for(int d2=0;d2<8;++d2){
                float a = b_fcg[col0+d2];
                #pragma unroll
                for(int kk=0;kk<8;++kk) a += gg[kk]*W_fcg[kk*256 + col0 + d2];
                o[d2] = acc[jl][d2]*rs + a;
            }
            float* ob = out + ((size_t)b*1024 + j0 + jl)*256 + col0;
            float4* o4 = reinterpret_cast<float4*>(ob);
            o4[0] = make_float4(o[0],o[1],o[2],o[3]);
            o4[1] = make_float4(o[4],o[5],o[6],o[7]);
        }
    }
}

extern "C" void kernel_launch(void* const* d_in, const int* in_sizes, int n_in,
                              void* d_out, int out_size, void* d_ws, size_t ws_size,
                              hipStream_t stream)
{
    const float* prev  = (const float*)d_in[0];
    const float* curr  = (const float*)d_in[1];
    const int*   edges = (const int*)  d_in[2];
    const float* W_pre = (const float*)d_in[3];
    const float* b_pre = (const float*)d_in[4];
    const float* W_cur = (const float*)d_in[5];
    const float* b_cur = (const float*)d_in[6];
    const float* W_fuse= (const float*)d_in[7];
    const float* b_fuse= (const float*)d_in[8];
    const float* W_ffn = (const float*)d_in[9];
    const float* b_ffn = (const float*)d_in[10];
    const float* W_fcc = (const float*)d_in[11];
    const float* b_fcc = (const float*)d_in[12];
    const float* W_fcg = (const float*)d_in[13];
    const float* b_fcg = (const float*)d_in[14];
    float* out = (float*)d_out;

    float* u_ws   = (float*)d_ws;          // 16384 floats
    float* v_ws   = u_ws  + 16384;         // 16384
    float* Gd_ws  = v_ws  + 16384;         // 32768
    float* cnt_ws = Gd_ws + 32768;         // 4096

    k_rows<<<dim3(2048), dim3(256), 0, stream>>>(prev, curr, W_pre, b_pre,
        W_cur, b_cur, W_fuse, b_fuse, u_ws, v_ws);
    k_cols<<<dim3(256), dim3(256), 0, stream>>>(edges, u_ws, v_ws,
        W_ffn, b_ffn, Gd_ws, cnt_ws);
    k_main<<<dim3(512), dim3(256), 0, stream>>>(prev, edges, u_ws, v_ws,
        Gd_ws, cnt_ws, W_ffn, W_fcc, b_fcc, W_fcg, b_fcg, out);
}